// Round 11
// baseline (237.081 us; speedup 1.0000x reference)
//
#include <hip/hip_runtime.h>
#include <stdint.h>

typedef unsigned short u16;
typedef __attribute__((ext_vector_type(8))) short short8;
typedef __attribute__((ext_vector_type(4))) short short4x;
typedef __attribute__((ext_vector_type(4))) float f32x4;

#define PI_F 3.14159265358979323846f
#define L_SEQ 2048
#define NFFT 4096
#define DM 1024
#define TW 3072
#define BATCH 4

__device__ __forceinline__ u16 f2bf(float f){
  union { float f; uint32_t u; } v; v.f = f;
  uint32_t r = v.u + 0x7fffu + ((v.u >> 16) & 1u);
  return (u16)(r >> 16);
}
__device__ __forceinline__ float bf2f(u16 h){
  union { uint32_t u; float f; } v; v.u = ((uint32_t)h) << 16;
  return v.f;
}

__device__ __forceinline__ void async16(const void* g, void* l){
  __builtin_amdgcn_global_load_lds(
      (const __attribute__((address_space(1))) void*)g,
      (__attribute__((address_space(3))) void*)l, 16, 0, 0);
}

// hardware sin/cos, input in REVOLUTIONS (angle = 2*pi*rev)
__device__ __forceinline__ void sincos_rev(float rev, float& sn, float& cs){
  asm("v_sin_f32 %0, %1" : "=v"(sn) : "v"(rev));
  asm("v_cos_f32 %0, %1" : "=v"(cs) : "v"(rev));
}

__device__ __forceinline__ float2 cmulf(float2 a, float c, float s){
  return make_float2(a.x*c - a.y*s, a.x*s + a.y*c);
}

__device__ __forceinline__ int P16(int i){ return i + (i >> 4); }

__device__ static constexpr int BR4[16] = {0,8,4,12,2,10,6,14,1,9,5,13,3,11,7,15};

template<int SGN>
__device__ __forceinline__ void fft16(float2* a){
  const float s = (float)SGN;
  static constexpr float tc[8]  = {1.f, 0.92387953f, 0.70710678f, 0.38268343f,
                                   0.f, -0.38268343f, -0.70710678f, -0.92387953f};
  static constexpr float ts_[8] = {0.f, -0.38268343f, -0.70710678f, -0.92387953f,
                                   -1.f, -0.92387953f, -0.70710678f, -0.38268343f};
  #pragma unroll
  for (int j = 0; j < 8; ++j){
    float2 u = a[j], v = a[j+8];
    float2 d = make_float2(u.x - v.x, u.y - v.y);
    a[j] = make_float2(u.x + v.x, u.y + v.y);
    a[j+8] = cmulf(d, tc[j], s*ts_[j]);
  }
  #pragma unroll
  for (int g = 0; g < 2; ++g){
    int b = g*8;
    #pragma unroll
    for (int j = 0; j < 4; ++j){
      float2 u = a[b+j], v = a[b+j+4];
      float2 d = make_float2(u.x - v.x, u.y - v.y);
      a[b+j] = make_float2(u.x + v.x, u.y + v.y);
      a[b+j+4] = cmulf(d, tc[2*j], s*ts_[2*j]);
    }
  }
  #pragma unroll
  for (int g = 0; g < 4; ++g){
    int b = g*4;
    #pragma unroll
    for (int j = 0; j < 2; ++j){
      float2 u = a[b+j], v = a[b+j+2];
      float2 d = make_float2(u.x - v.x, u.y - v.y);
      a[b+j] = make_float2(u.x + v.x, u.y + v.y);
      a[b+j+2] = (j == 0) ? d : cmulf(d, 0.f, -s);
    }
  }
  #pragma unroll
  for (int g = 0; g < 8; ++g){
    int b = g*2;
    float2 u = a[b], v = a[b+1];
    a[b] = make_float2(u.x + v.x, u.y + v.y);
    a[b+1] = make_float2(u.x - v.x, u.y - v.y);
  }
}

// ---------------- convert u (fp32 -> bf16), vectorized ----------------
__global__ void k_convert_u(const float4* __restrict__ in, u16* __restrict__ outp, int n4){
  int idx = blockIdx.x * blockDim.x + threadIdx.x;
  int stride = gridDim.x * blockDim.x;
  for (int i = idx; i < n4; i += stride){
    float4 v = in[i];
    u16 r0 = f2bf(v.x), r1 = f2bf(v.y), r2 = f2bf(v.z), r3 = f2bf(v.w);
    u16* o = outp + (size_t)i * 4;
    o[0] = r0; o[1] = r1; o[2] = r2; o[3] = r3;
  }
}

// ---------------- transpose weight fp32 (K,N) -> bf16 (N,K) ----------------
__global__ void k_transpose_w(const float* __restrict__ in, u16* __restrict__ outp, int K, int N){
  __shared__ float tile[32][33];
  int n0 = blockIdx.x * 32, k0 = blockIdx.y * 32;
  int x = threadIdx.x, y = threadIdx.y;
  for (int i = 0; i < 4; ++i)
    tile[y + i*8][x] = in[(size_t)(k0 + y + i*8) * N + n0 + x];
  __syncthreads();
  for (int i = 0; i < 4; ++i)
    outp[(size_t)(n0 + y + i*8) * K + k0 + x] = f2bf(tile[x][y + i*8]);
}

// ---------------- filter MLP: H2T (64 x 2048, TRANSPOSED) ----------------
__global__ void k_filter_h2(const float* __restrict__ w0, const float* __restrict__ b0, const float* __restrict__ f0,
                            const float* __restrict__ w1, const float* __restrict__ b1, const float* __restrict__ f1,
                            const float* __restrict__ w2, const float* __restrict__ b2, const float* __restrict__ f2,
                            float* __restrict__ H2T){
  int t = blockIdx.x;
  int j = threadIdx.x; // 0..63
  float tn = t * (1.0f / 2047.0f);
  float ph = 1e-4f * 2.0f * PI_F * (float)t * (1.0f / 2048.0f);
  float z0 = tn, z1 = cosf(ph), z2 = -sinf(ph);
  __shared__ float hs[64];
  float pre = z0 * w0[j] + z1 * w0[64 + j] + z2 * w0[128 + j] + b0[j];
  float h = sinf(f0[j] * pre);
  hs[j] = h;
  __syncthreads();
  float acc = b1[j];
  for (int i = 0; i < 64; ++i) acc += hs[i] * w1[i*64 + j];
  h = sinf(f1[j] * acc);
  __syncthreads();
  hs[j] = h;
  __syncthreads();
  acc = b2[j];
  for (int i = 0; i < 64; ++i) acc += hs[i] * w2[i*64 + j];
  h = sinf(f2[j] * acc);
  H2T[j * L_SEQ + t] = h;
}

// ---------------- filter spectra: radix-16 register FFT, 2 channels packed ----
__global__ __launch_bounds__(256) void k_filter_fft16(const float* __restrict__ H2T,
                                                      const float* __restrict__ w3,
                                                      float2* __restrict__ Kf){
  int c0 = blockIdx.x * 2;
  int t = threadIdx.x;
  __shared__ float2 S[4352];
  __shared__ float wcol[2][64];
  if (t < 64){ wcol[0][t] = w3[t * DM + c0]; wcol[1][t] = w3[t * DM + c0 + 1]; }
  __syncthreads();
  const int n1 = t & 15, hi = t >> 4;
  float absd0 = 3.070113457325394f + 12.280453829301576f * ((float)c0 * (1.0f / 1023.0f));
  float absd1 = 3.070113457325394f + 12.280453829301576f * ((float)(c0+1) * (1.0f / 1023.0f));
  float sa[8] = {0,0,0,0,0,0,0,0}, sb[8] = {0,0,0,0,0,0,0,0};
  for (int j = 0; j < 64; ++j){
    float wa = wcol[0][j], wb = wcol[1][j];
    const float* hrow = H2T + j * L_SEQ + t;
    #pragma unroll
    for (int n3 = 0; n3 < 8; ++n3){
      float h = hrow[n3 << 8];
      sa[n3] += h * wa; sb[n3] += h * wb;
    }
  }
  float2 r[16];
  #pragma unroll
  for (int n3 = 0; n3 < 8; ++n3){
    int n = t + (n3 << 8);
    float tn = (float)n * (1.0f / 2047.0f);
    r[n3] = make_float2(sa[n3] * __expf(-tn * absd0), sb[n3] * __expf(-tn * absd1));
    r[n3 + 8] = make_float2(0.f, 0.f);
  }
  fft16<1>(r);
  #pragma unroll
  for (int k3 = 0; k3 < 16; ++k3){
    float sn, cs; sincos_rev(-(float)(hi * k3) * (1.0f/256.0f), sn, cs);
    S[P16(k3*256 + hi*16 + n1)] = cmulf(r[BR4[k3]], cs, sn);
  }
  __syncthreads();
  #pragma unroll
  for (int n2 = 0; n2 < 16; ++n2)
    r[n2] = S[P16(hi*256 + n2*16 + n1)];
  __syncthreads();
  fft16<1>(r);
  #pragma unroll
  for (int k2 = 0; k2 < 16; ++k2){
    float sn, cs; sincos_rev(-(float)(n1 * (hi + 16*k2)) * (1.0f/4096.0f), sn, cs);
    S[P16(k2*256 + hi*16 + n1)] = cmulf(r[BR4[k2]], cs, sn);
  }
  __syncthreads();
  #pragma unroll
  for (int m = 0; m < 16; ++m)
    r[m] = S[P16(hi*256 + n1*16 + m)];
  __syncthreads();
  fft16<1>(r);
  #pragma unroll
  for (int k1 = 0; k1 < 16; ++k1)
    S[P16(t + (k1 << 8))] = r[BR4[k1]];
  __syncthreads();
  const float inv = 1.0f / (float)NFFT;
  float2* kf0 = Kf + (size_t)c0 * NFFT;
  float2* kf1 = kf0 + NFFT;
  int mt = (256 - t) & 255;
  #pragma unroll
  for (int k1 = 0; k1 < 16; ++k1){
    int k = t + (k1 << 8);
    int mk1 = (t == 0) ? ((16 - k1) & 15) : (15 - k1);
    float2 Zk = r[BR4[k1]];
    float2 Zm = S[P16(mt + (mk1 << 8))];
    float gar = 0.5f*(Zk.x + Zm.x), gai = 0.5f*(Zk.y - Zm.y);
    float gbr = 0.5f*(Zk.y + Zm.y), gbi = 0.5f*(Zm.x - Zk.x);
    kf0[k] = make_float2(gar*inv, gai*inv);
    kf1[k] = make_float2(gbr*inv, gbi*inv);
  }
}

// =================== 2-phase/K-tile 8-wave GEMM (R8 config, best measured) ===================
__device__ __forceinline__ void gbar(){ __builtin_amdgcn_s_barrier(); }
__device__ __forceinline__ void lgk0(){
  asm volatile("s_waitcnt lgkmcnt(0)" ::: "memory");
  __builtin_amdgcn_sched_barrier(0);
}
template<int V>
__device__ __forceinline__ void waitvm(){
  if constexpr (V == 8) asm volatile("s_waitcnt vmcnt(8)" ::: "memory");
  else if constexpr (V == 6) asm volatile("s_waitcnt vmcnt(6)" ::: "memory");
  else asm volatile("s_waitcnt vmcnt(0)" ::: "memory");
  __builtin_amdgcn_sched_barrier(0);
}

template<int BM, int BN, bool OUT_BF16>
__global__ __launch_bounds__(512, 2) void k_gemm8(const u16* __restrict__ A, const u16* __restrict__ Bt,
                                                  const float* __restrict__ bias, void* __restrict__ Cout,
                                                  int M, int N, int K){
  constexpr int MR  = BM / 32;
  constexpr int NR  = BN / 64;
  constexpr int LA  = BM / 128;
  constexpr int LB  = BN / 128;
  constexpr int V   = 2 * (LA + LB);
  static_assert(LA * 128 == BM && LB * 128 == BN, "stage divisors");
  __shared__ __align__(16) u16 lds[2 * 64 * (BM + BN)];
  const int tid = threadIdx.x;
  const int lane = tid & 63, w = tid >> 6;
  const int wm = w >> 2, wn = w & 3;
  const int lr = lane & 15, lk8 = (lane >> 4) * 8;
  const int NT = K >> 6;

  // n-fast decomposition: each XCD owns an m-panel (A L2-resident, B via L3)
  const int NNT = N / BN;
  int nwg = gridDim.x;
  int swz = (blockIdx.x & 7) * (nwg >> 3) + (blockIdx.x >> 3);
  int m0 = (swz / NNT) * BM;
  int n0 = (swz % NNT) * BN;

  u16* baseA = lds;
  u16* baseB = lds + 2 * 64 * BM;

  auto stageA = [&](int kts, int db, int kh){
    int kc0 = (kts << 6) + kh * 32;
    u16* slab = baseA + db * (BM * 64) + kh * (BM * 32);
    #pragma unroll
    for (int q = 0; q < LA; ++q){
      int row = q * 128 + (tid >> 2);
      int cl = ((tid & 3) * 8) ^ (((row >> 1) & 3) << 3);
      async16(A + (size_t)(m0 + row) * K + kc0 + cl, slab + q * 4096 + (w << 9));
    }
  };
  auto stageB = [&](int kts, int db, int kh){
    int kc0 = (kts << 6) + kh * 32;
    u16* slab = baseB + db * (BN * 64) + kh * (BN * 32);
    #pragma unroll
    for (int q = 0; q < LB; ++q){
      int row = q * 128 + (tid >> 2);
      int cl = ((tid & 3) * 8) ^ (((row >> 1) & 3) << 3);
      async16(Bt + (size_t)(n0 + row) * K + kc0 + cl, slab + q * 4096 + (w << 9));
    }
  };

  f32x4 acc[MR][NR] = {};
  short8 af[MR], bf[NR];

  auto readA = [&](int db, int kh){
    const u16* base = baseA + db * (BM * 64) + kh * (BM * 32);
    #pragma unroll
    for (int i = 0; i < MR; ++i){
      int ar = wm * (BM / 2) + i * 16 + lr;
      af[i] = *(const short8*)&base[ar * 32 + (lk8 ^ (((ar >> 1) & 3) << 3))];
    }
  };
  auto readB = [&](int db, int kh){
    const u16* base = baseB + db * (BN * 64) + kh * (BN * 32);
    #pragma unroll
    for (int j = 0; j < NR; ++j){
      int br = wn * (BN / 4) + j * 16 + lr;
      bf[j] = *(const short8*)&base[br * 32 + (lk8 ^ (((br >> 1) & 3) << 3))];
    }
  };

#define MFMA_FULL                                                              \
  __builtin_amdgcn_s_setprio(1);                                               \
  _Pragma("unroll")                                                            \
  for (int i = 0; i < MR; ++i)                                                 \
    _Pragma("unroll")                                                          \
    for (int j = 0; j < NR; ++j)                                               \
      acc[i][j] = __builtin_amdgcn_mfma_f32_16x16x32_bf16(                     \
          af[i], bf[j], acc[i][j], 0, 0, 0);                                   \
  __builtin_amdgcn_s_setprio(0);

  // prologue: stage kt0 (both kh) + kt1 kh0
  stageA(0, 0, 0); stageB(0, 0, 0);
  stageA(0, 0, 1); stageB(0, 0, 1);
  stageA(1, 1, 0); stageB(1, 1, 0);
  waitvm<V>();
  gbar();

  for (int kt = 0; kt < NT; ++kt){
    int b = kt & 1, bn2 = b ^ 1;
    int t1 = (kt + 1 < NT) ? kt + 1 : 0;
    int t2 = (kt + 2 < NT) ? kt + 2 : 0;
    // phase 0 (kh0)
    readB(b, 0); readA(b, 0);
    stageA(t1, bn2, 1); stageB(t1, bn2, 1);
    gbar(); lgk0();
    MFMA_FULL
    waitvm<V>();
    gbar();
    // phase 1 (kh1)
    readB(b, 1); readA(b, 1);
    stageA(t2, b, 0); stageB(t2, b, 0);
    gbar(); lgk0();
    MFMA_FULL
    waitvm<V>();
    gbar();
  }
#undef MFMA_FULL

  waitvm<0>();
  gbar();
  if constexpr (OUT_BF16){
    constexpr int BST = BN + 8;
    u16* lbuf = lds;
    #pragma unroll
    for (int j = 0; j < NR; ++j){
      int col = wn * (BN / 4) + j * 16 + lr;
      float bv = bias[n0 + col];
      #pragma unroll
      for (int i = 0; i < MR; ++i){
        int rw = wm * (BM / 2) + i * 16 + (lane >> 4) * 4;
        #pragma unroll
        for (int r = 0; r < 4; ++r)
          lbuf[(rw + r) * BST + col] = f2bf(acc[i][j][r] + bv);
      }
    }
    gbar();
    constexpr int ROWCH = BN / 8;
    constexpr int CHUNKS = BM * ROWCH;
    #pragma unroll
    for (int q = 0; q < CHUNKS / 512; ++q){
      int c = tid + q * 512;
      int row = c / ROWCH, col8 = (c % ROWCH) * 8;
      f32x4 vv = *(const f32x4*)&lbuf[row * BST + col8];
      *(f32x4*)((u16*)Cout + (size_t)(m0 + row) * N + n0 + col8) = vv;
    }
  } else {
    constexpr int BSTF = BN + 4;
    float* lbuf = (float*)lds;
    constexpr int ROWCHF = BN / 4;
    constexpr int CHUNKSF = (BM / 2) * ROWCHF;
    #pragma unroll
    for (int p = 0; p < 2; ++p){
      if (wm == p){
        #pragma unroll
        for (int j = 0; j < NR; ++j){
          int col = wn * (BN / 4) + j * 16 + lr;
          float bv = bias[n0 + col];
          #pragma unroll
          for (int i = 0; i < MR; ++i){
            int rl = i * 16 + (lane >> 4) * 4;
            #pragma unroll
            for (int r = 0; r < 4; ++r)
              lbuf[(rl + r) * BSTF + col] = acc[i][j][r] + bv;
          }
        }
      }
      gbar();
      #pragma unroll
      for (int q = 0; q < CHUNKSF / 512; ++q){
        int c = tid + q * 512;
        int row = c / ROWCHF, col4 = (c % ROWCHF) * 4;
        f32x4 vv = *(const f32x4*)&lbuf[row * BSTF + col4];
        *(f32x4*)((float*)Cout + (size_t)(m0 + p * (BM / 2) + row) * N + n0 + col4) = vv;
      }
      gbar();
    }
  }
}

// ---------------- short conv + gate + transpose to (b,d,l), vectorized ----------------
__device__ __forceinline__ int ogcol(int c, int t){ return c * 136 + (t ^ (((c >> 3) & 7) << 4)); }

__global__ __launch_bounds__(256) void k_shortconv(const u16* __restrict__ up, const float* __restrict__ sw,
                            const float* __restrict__ sb,
                            u16* __restrict__ gOut, u16* __restrict__ x0Out){
  __shared__ u16 og[2][64 * 136];
  const int t0 = blockIdx.x * 128;
  const int c0 = blockIdx.y * 64;
  const int b  = blockIdx.z;
  const int tid = threadIdx.x;
  const int c8 = (tid & 7) * 8;
  const int tt = (tid >> 3) * 4;
  const int cg = c0 + c8;

  auto conv_group = [&](int g2, float out[8][4]){
    const f32x4* wp = (const f32x4*)(sw + (size_t)(g2 * DM + cg) * 3);
    f32x4 w03 = wp[0], w47 = wp[1], w8b = wp[2], wcf = wp[3], wgj = wp[4], wkn = wp[5];
    float wv[24];
    #pragma unroll
    for (int x = 0; x < 4; ++x){ wv[x] = w03[x]; wv[4+x] = w47[x]; wv[8+x] = w8b[x];
                                 wv[12+x] = wcf[x]; wv[16+x] = wgj[x]; wv[20+x] = wkn[x]; }
    const f32x4* bp = (const f32x4*)(sb + g2 * DM + cg);
    f32x4 b03 = bp[0], b47 = bp[1];
    float bv[8];
    #pragma unroll
    for (int x = 0; x < 4; ++x){ bv[x] = b03[x]; bv[4+x] = b47[x]; }
    const u16* base = up + ((size_t)(b * L_SEQ + t0 + tt - 2)) * TW + g2 * DM + cg;
    short8 rows[6];
    #pragma unroll
    for (int r = 0; r < 6; ++r){
      int t = t0 + tt - 2 + r;
      if (t >= 0) rows[r] = *(const short8*)(base + (size_t)r * TW);
      else rows[r] = (short8)0;
    }
    #pragma unroll
    for (int j = 0; j < 8; ++j){
      float w0 = wv[j*3], w1 = wv[j*3+1], w2 = wv[j*3+2], bb = bv[j];
      #pragma unroll
      for (int q = 0; q < 4; ++q){
        out[j][q] = w0 * bf2f((u16)rows[q][j]) + w1 * bf2f((u16)rows[q+1][j])
                  + w2 * bf2f((u16)rows[q+2][j]) + bb;
      }
    }
  };

  float x1v[8][4], gv[8][4], x0v[8][4];
  conv_group(1, x1v);
  conv_group(2, gv);
  #pragma unroll
  for (int j = 0; j < 8; ++j)
    #pragma unroll
    for (int q = 0; q < 4; ++q) gv[j][q] *= x1v[j][q];
  conv_group(0, x0v);

  #pragma unroll
  for (int j = 0; j < 8; ++j){
    short4x px, pg;
    #pragma unroll
    for (int q = 0; q < 4; ++q){ px[q] = (short)f2bf(x0v[j][q]); pg[q] = (short)f2bf(gv[j][q]); }
    int col = ogcol(c8 + j, tt);
    *(short4x*)&og[0][col] = px;
    *(short4x*)&og[1][col] = pg;
  }
  __syncthreads();

  #pragma unroll
  for (int q = 0; q < 4; ++q){
    int ch = tid + q * 256;
    int c = ch >> 4, t8 = (ch & 15) * 8;
    size_t gb = ((size_t)(b * DM + c0 + c)) * L_SEQ + t0 + t8;
    f32x4 v0 = *(const f32x4*)&og[0][ogcol(c, t8)];
    *(f32x4*)(x0Out + gb) = v0;
    f32x4 v1 = *(const f32x4*)&og[1][ogcol(c, t8)];
    *(f32x4*)(gOut + gb) = v1;
  }
}

// ---- FFT conv v2: batch-fused, twiddles cached in registers (2 families) ----
__global__ __launch_bounds__(256) void k_fftconv(const u16* __restrict__ g, const u16* __restrict__ x0,
                          const float2* __restrict__ Kf, const float* __restrict__ fbias,
                          u16* __restrict__ z){
  int c0 = blockIdx.x * 2;
  int t = threadIdx.x;
  __shared__ float2 S[4352];
  const int n1 = t & 15, hi = t >> 4;
  // two twiddle families cover all 6 stages (inverse = conjugate)
  float t1c[16], t1s[16], t2c[16], t2s[16];
  #pragma unroll
  for (int k = 0; k < 16; ++k){
    sincos_rev(-(float)(hi * k) * (1.0f/256.0f), t1s[k], t1c[k]);
    sincos_rev(-(float)(n1 * (hi + 16*k)) * (1.0f/4096.0f), t2s[k], t2c[k]);
  }
  const float2* kf0 = Kf + (size_t)c0 * NFFT;
  const float2* kf1 = kf0 + NFFT;
  const float fb0 = fbias[c0], fb1 = fbias[c0+1];
  const int mt = (256 - t) & 255;

  for (int b = 0; b < BATCH; ++b){
    const size_t row0 = ((size_t)(b * DM + c0)) * L_SEQ;
    const size_t row1 = row0 + L_SEQ;
    float2 r[16];
    #pragma unroll
    for (int n3 = 0; n3 < 8; ++n3){
      int n = t + (n3 << 8);
      r[n3] = make_float2(bf2f(g[row0 + n]), bf2f(g[row1 + n]));
      r[n3 + 8] = make_float2(0.f, 0.f);
    }
    fft16<1>(r);
    __syncthreads();   // S free from previous batch's final gathers
    #pragma unroll
    for (int k3 = 0; k3 < 16; ++k3)
      S[P16(k3*256 + hi*16 + n1)] = cmulf(r[BR4[k3]], t1c[k3], t1s[k3]);
    __syncthreads();
    #pragma unroll
    for (int n2 = 0; n2 < 16; ++n2)
      r[n2] = S[P16(hi*256 + n2*16 + n1)];
    __syncthreads();
    fft16<1>(r);
    #pragma unroll
    for (int k2 = 0; k2 < 16; ++k2)
      S[P16(k2*256 + hi*16 + n1)] = cmulf(r[BR4[k2]], t2c[k2], t2s[k2]);
    __syncthreads();
    #pragma unroll
    for (int m = 0; m < 16; ++m)
      r[m] = S[P16(hi*256 + n1*16 + m)];
    __syncthreads();
    fft16<1>(r);
    #pragma unroll
    for (int k1 = 0; k1 < 16; ++k1)
      S[P16(t + (k1 << 8))] = r[BR4[k1]];
    __syncthreads();
    float2 y[16];
    #pragma unroll
    for (int k1 = 0; k1 < 16; ++k1){
      int k = t + (k1 << 8);
      int mk1 = (t == 0) ? ((16 - k1) & 15) : (15 - k1);
      float2 Zk = r[BR4[k1]];
      float2 Zm = S[P16(mt + (mk1 << 8))];
      float2 K0 = kf0[k], K1 = kf1[k];
      float gar = 0.5f*(Zk.x + Zm.x), gai = 0.5f*(Zk.y - Zm.y);
      float gbr = 0.5f*(Zk.y + Zm.y), gbi = 0.5f*(Zm.x - Zk.x);
      float yar = gar*K0.x - gai*K0.y, yai = gar*K0.y + gai*K0.x;
      float ybr = gbr*K1.x - gbi*K1.y, ybi = gbr*K1.y + gbi*K1.x;
      y[k1] = make_float2(yar - ybi, yai + ybr);
    }
    fft16<-1>(y);
    __syncthreads();
    #pragma unroll
    for (int n3 = 0; n3 < 16; ++n3)
      S[P16(n3*256 + hi*16 + n1)] = cmulf(y[BR4[n3]], t1c[n3], -t1s[n3]);
    __syncthreads();
    #pragma unroll
    for (int m2 = 0; m2 < 16; ++m2)
      r[m2] = S[P16(hi*256 + m2*16 + n1)];
    __syncthreads();
    fft16<-1>(r);
    #pragma unroll
    for (int nn2 = 0; nn2 < 16; ++nn2)
      S[P16(nn2*256 + hi*16 + n1)] = cmulf(r[BR4[nn2]], t2c[nn2], -t2s[nn2]);
    __syncthreads();
    #pragma unroll
    for (int m = 0; m < 16; ++m)
      r[m] = S[P16(hi*256 + n1*16 + m)];
    fft16<-1>(r);
    #pragma unroll
    for (int q = 0; q < 8; ++q){
      int n = t + (q << 8);
      float2 val = r[BR4[q]];
      float g0 = bf2f(g[row0 + n]), g1 = bf2f(g[row1 + n]);
      float x00 = bf2f(x0[row0 + n]), x01 = bf2f(x0[row1 + n]);
      z[row0 + n] = f2bf((val.x + g0*fb0) * x00);
      z[row1 + n] = f2bf((val.y + g1*fb1) * x01);
    }
  }
}

// ---------------- transpose z: (b,d,l) bf16 -> (b,l,d) bf16 ----------------
__global__ void k_transpose_z(const u16* __restrict__ zin, u16* __restrict__ zout){
  __shared__ u16 tile[32][33];
  int l0 = blockIdx.x * 32, d0 = blockIdx.y * 32, b = blockIdx.z;
  int x = threadIdx.x, y = threadIdx.y;
  for (int i = 0; i < 4; ++i){
    int d = d0 + y + i*8;
    tile[y + i*8][x] = zin[((size_t)(b * DM + d)) * L_SEQ + l0 + x];
  }
  __syncthreads();
  for (int i = 0; i < 4; ++i){
    int l = l0 + y + i*8;
    zout[((size_t)(b * L_SEQ + l)) * DM + d0 + x] = tile[x][y + i*8];
  }
}

extern "C" void kernel_launch(void* const* d_in, const int* in_sizes, int n_in,
                              void* d_out, int out_size, void* d_ws, size_t ws_size,
                              hipStream_t stream){
  (void)in_sizes; (void)n_in; (void)out_size; (void)ws_size;
  const float* u       = (const float*)d_in[0];
  const float* in_w    = (const float*)d_in[1];
  const float* in_b    = (const float*)d_in[2];
  const float* short_w = (const float*)d_in[3];
  const float* short_b = (const float*)d_in[4];
  const float* w0 = (const float*)d_in[5];
  const float* b0 = (const float*)d_in[6];
  const float* f0 = (const float*)d_in[7];
  const float* w1 = (const float*)d_in[8];
  const float* b1 = (const float*)d_in[9];
  const float* f1 = (const float*)d_in[10];
  const float* w2 = (const float*)d_in[11];
  const float* b2 = (const float*)d_in[12];
  const float* f2 = (const float*)d_in[13];
  const float* w3 = (const float*)d_in[14];
  const float* fbias = (const float*)d_in[15];
  const float* out_w = (const float*)d_in[16];
  const float* out_b = (const float*)d_in[17];
  float* out = (float*)d_out;

  char* ws = (char*)d_ws;
  size_t off = 0;
  auto alloc = [&](size_t bytes)->void*{
    void* p = ws + off; off += (bytes + 255) & ~(size_t)255; return p;
  };
  const int M = BATCH * L_SEQ; // 8192
  u16*   u_bf  = (u16*)  alloc((size_t)M * DM * 2);       // later reused as z
  u16*   inwT  = (u16*)  alloc((size_t)TW * DM * 2);
  u16*   outwT = (u16*)  alloc((size_t)DM * DM * 2);
  float* H2T   = (float*)alloc((size_t)L_SEQ * 64 * 4);
  float2* Kf   = (float2*)alloc((size_t)DM * NFFT * 8);
  u16*   up    = (u16*)  alloc((size_t)M * TW * 2);       // later reused as zT
  u16*   gbuf  = (u16*)  alloc((size_t)BATCH * DM * L_SEQ * 2);
  u16*   x0buf = (u16*)  alloc((size_t)BATCH * DM * L_SEQ * 2);
  u16*   z  = u_bf;   // alias: u_bf dead after gemm1
  u16*   zT = up;     // alias: up dead after shortconv

  k_convert_u<<<2048, 256, 0, stream>>>((const float4*)u, u_bf, (M * DM) / 4);
  k_transpose_w<<<dim3(TW/32, DM/32), dim3(32, 8), 0, stream>>>(in_w, inwT, DM, TW);
  k_transpose_w<<<dim3(DM/32, DM/32), dim3(32, 8), 0, stream>>>(out_w, outwT, DM, DM);
  k_filter_h2<<<L_SEQ, 64, 0, stream>>>(w0, b0, f0, w1, b1, f1, w2, b2, f2, H2T);
  k_filter_fft16<<<DM/2, 256, 0, stream>>>(H2T, w3, Kf);
  k_gemm8<128, 384, true><<<dim3((M/128)*(TW/384)), 512, 0, stream>>>(u_bf, inwT, in_b, up, M, TW, DM);
  k_shortconv<<<dim3(L_SEQ/128, DM/64, BATCH), 256, 0, stream>>>(up, short_w, short_b, gbuf, x0buf);
  k_fftconv<<<dim3(DM/2), 256, 0, stream>>>(gbuf, x0buf, Kf, fbias, z);
  k_transpose_z<<<dim3(L_SEQ/32, DM/32, BATCH), dim3(32, 8), 0, stream>>>(z, zT);
  k_gemm8<256, 128, false><<<dim3((M/256)*(DM/128)), 512, 0, stream>>>(zT, outwT, out_b, out, M, DM, DM);
}

// Round 12
// 197.315 us; speedup vs baseline: 1.2015x; 1.2015x over previous
//
#include <hip/hip_runtime.h>
#include <stdint.h>

typedef unsigned short u16;
typedef __attribute__((ext_vector_type(8))) short short8;
typedef __attribute__((ext_vector_type(4))) short short4x;
typedef __attribute__((ext_vector_type(4))) float f32x4;

#define PI_F 3.14159265358979323846f
#define L_SEQ 2048
#define NFFT 4096
#define DM 1024
#define TW 3072
#define BATCH 4

__device__ __forceinline__ u16 f2bf(float f){
  union { float f; uint32_t u; } v; v.f = f;
  uint32_t r = v.u + 0x7fffu + ((v.u >> 16) & 1u);
  return (u16)(r >> 16);
}
__device__ __forceinline__ float bf2f(u16 h){
  union { uint32_t u; float f; } v; v.u = ((uint32_t)h) << 16;
  return v.f;
}

__device__ __forceinline__ void async16(const void* g, void* l){
  __builtin_amdgcn_global_load_lds(
      (const __attribute__((address_space(1))) void*)g,
      (__attribute__((address_space(3))) void*)l, 16, 0, 0);
}

// hardware sin/cos, input in REVOLUTIONS (angle = 2*pi*rev)
__device__ __forceinline__ void sincos_rev(float rev, float& sn, float& cs){
  asm("v_sin_f32 %0, %1" : "=v"(sn) : "v"(rev));
  asm("v_cos_f32 %0, %1" : "=v"(cs) : "v"(rev));
}

__device__ __forceinline__ float2 cmulf(float2 a, float c, float s){
  return make_float2(a.x*c - a.y*s, a.x*s + a.y*c);
}

__device__ __forceinline__ int P16(int i){ return i + (i >> 4); }

__device__ static constexpr int BR4[16] = {0,8,4,12,2,10,6,14,1,9,5,13,3,11,7,15};

template<int SGN>
__device__ __forceinline__ void fft16(float2* a){
  const float s = (float)SGN;
  static constexpr float tc[8]  = {1.f, 0.92387953f, 0.70710678f, 0.38268343f,
                                   0.f, -0.38268343f, -0.70710678f, -0.92387953f};
  static constexpr float ts_[8] = {0.f, -0.38268343f, -0.70710678f, -0.92387953f,
                                   -1.f, -0.92387953f, -0.70710678f, -0.38268343f};
  #pragma unroll
  for (int j = 0; j < 8; ++j){
    float2 u = a[j], v = a[j+8];
    float2 d = make_float2(u.x - v.x, u.y - v.y);
    a[j] = make_float2(u.x + v.x, u.y + v.y);
    a[j+8] = cmulf(d, tc[j], s*ts_[j]);
  }
  #pragma unroll
  for (int g = 0; g < 2; ++g){
    int b = g*8;
    #pragma unroll
    for (int j = 0; j < 4; ++j){
      float2 u = a[b+j], v = a[b+j+4];
      float2 d = make_float2(u.x - v.x, u.y - v.y);
      a[b+j] = make_float2(u.x + v.x, u.y + v.y);
      a[b+j+4] = cmulf(d, tc[2*j], s*ts_[2*j]);
    }
  }
  #pragma unroll
  for (int g = 0; g < 4; ++g){
    int b = g*4;
    #pragma unroll
    for (int j = 0; j < 2; ++j){
      float2 u = a[b+j], v = a[b+j+2];
      float2 d = make_float2(u.x - v.x, u.y - v.y);
      a[b+j] = make_float2(u.x + v.x, u.y + v.y);
      a[b+j+2] = (j == 0) ? d : cmulf(d, 0.f, -s);
    }
  }
  #pragma unroll
  for (int g = 0; g < 8; ++g){
    int b = g*2;
    float2 u = a[b], v = a[b+1];
    a[b] = make_float2(u.x + v.x, u.y + v.y);
    a[b+1] = make_float2(u.x - v.x, u.y - v.y);
  }
}

// ---------------- convert u (fp32 -> bf16), vectorized ----------------
__global__ void k_convert_u(const float4* __restrict__ in, u16* __restrict__ outp, int n4){
  int idx = blockIdx.x * blockDim.x + threadIdx.x;
  int stride = gridDim.x * blockDim.x;
  for (int i = idx; i < n4; i += stride){
    float4 v = in[i];
    u16 r0 = f2bf(v.x), r1 = f2bf(v.y), r2 = f2bf(v.z), r3 = f2bf(v.w);
    u16* o = outp + (size_t)i * 4;
    o[0] = r0; o[1] = r1; o[2] = r2; o[3] = r3;
  }
}

// ---------------- transpose weight fp32 (K,N) -> bf16 (N,K) ----------------
__global__ void k_transpose_w(const float* __restrict__ in, u16* __restrict__ outp, int K, int N){
  __shared__ float tile[32][33];
  int n0 = blockIdx.x * 32, k0 = blockIdx.y * 32;
  int x = threadIdx.x, y = threadIdx.y;
  for (int i = 0; i < 4; ++i)
    tile[y + i*8][x] = in[(size_t)(k0 + y + i*8) * N + n0 + x];
  __syncthreads();
  for (int i = 0; i < 4; ++i)
    outp[(size_t)(n0 + y + i*8) * K + k0 + x] = f2bf(tile[x][y + i*8]);
}

// ---------------- filter MLP: H2T (64 x 2048, TRANSPOSED) ----------------
__global__ void k_filter_h2(const float* __restrict__ w0, const float* __restrict__ b0, const float* __restrict__ f0,
                            const float* __restrict__ w1, const float* __restrict__ b1, const float* __restrict__ f1,
                            const float* __restrict__ w2, const float* __restrict__ b2, const float* __restrict__ f2,
                            float* __restrict__ H2T){
  int t = blockIdx.x;
  int j = threadIdx.x; // 0..63
  float tn = t * (1.0f / 2047.0f);
  float ph = 1e-4f * 2.0f * PI_F * (float)t * (1.0f / 2048.0f);
  float z0 = tn, z1 = cosf(ph), z2 = -sinf(ph);
  __shared__ float hs[64];
  float pre = z0 * w0[j] + z1 * w0[64 + j] + z2 * w0[128 + j] + b0[j];
  float h = sinf(f0[j] * pre);
  hs[j] = h;
  __syncthreads();
  float acc = b1[j];
  for (int i = 0; i < 64; ++i) acc += hs[i] * w1[i*64 + j];
  h = sinf(f1[j] * acc);
  __syncthreads();
  hs[j] = h;
  __syncthreads();
  acc = b2[j];
  for (int i = 0; i < 64; ++i) acc += hs[i] * w2[i*64 + j];
  h = sinf(f2[j] * acc);
  H2T[j * L_SEQ + t] = h;
}

// ---------------- filter spectra: radix-16 register FFT, 2 channels packed ----
__global__ __launch_bounds__(256) void k_filter_fft16(const float* __restrict__ H2T,
                                                      const float* __restrict__ w3,
                                                      float2* __restrict__ Kf){
  int c0 = blockIdx.x * 2;
  int t = threadIdx.x;
  __shared__ float2 S[4352];
  __shared__ float wcol[2][64];
  if (t < 64){ wcol[0][t] = w3[t * DM + c0]; wcol[1][t] = w3[t * DM + c0 + 1]; }
  __syncthreads();
  const int n1 = t & 15, hi = t >> 4;
  float absd0 = 3.070113457325394f + 12.280453829301576f * ((float)c0 * (1.0f / 1023.0f));
  float absd1 = 3.070113457325394f + 12.280453829301576f * ((float)(c0+1) * (1.0f / 1023.0f));
  float sa[8] = {0,0,0,0,0,0,0,0}, sb[8] = {0,0,0,0,0,0,0,0};
  for (int j = 0; j < 64; ++j){
    float wa = wcol[0][j], wb = wcol[1][j];
    const float* hrow = H2T + j * L_SEQ + t;
    #pragma unroll
    for (int n3 = 0; n3 < 8; ++n3){
      float h = hrow[n3 << 8];
      sa[n3] += h * wa; sb[n3] += h * wb;
    }
  }
  float2 r[16];
  #pragma unroll
  for (int n3 = 0; n3 < 8; ++n3){
    int n = t + (n3 << 8);
    float tn = (float)n * (1.0f / 2047.0f);
    r[n3] = make_float2(sa[n3] * __expf(-tn * absd0), sb[n3] * __expf(-tn * absd1));
    r[n3 + 8] = make_float2(0.f, 0.f);
  }
  fft16<1>(r);
  #pragma unroll
  for (int k3 = 0; k3 < 16; ++k3){
    float sn, cs; sincos_rev(-(float)(hi * k3) * (1.0f/256.0f), sn, cs);
    S[P16(k3*256 + hi*16 + n1)] = cmulf(r[BR4[k3]], cs, sn);
  }
  __syncthreads();
  #pragma unroll
  for (int n2 = 0; n2 < 16; ++n2)
    r[n2] = S[P16(hi*256 + n2*16 + n1)];
  __syncthreads();
  fft16<1>(r);
  #pragma unroll
  for (int k2 = 0; k2 < 16; ++k2){
    float sn, cs; sincos_rev(-(float)(n1 * (hi + 16*k2)) * (1.0f/4096.0f), sn, cs);
    S[P16(k2*256 + hi*16 + n1)] = cmulf(r[BR4[k2]], cs, sn);
  }
  __syncthreads();
  #pragma unroll
  for (int m = 0; m < 16; ++m)
    r[m] = S[P16(hi*256 + n1*16 + m)];
  __syncthreads();
  fft16<1>(r);
  #pragma unroll
  for (int k1 = 0; k1 < 16; ++k1)
    S[P16(t + (k1 << 8))] = r[BR4[k1]];
  __syncthreads();
  const float inv = 1.0f / (float)NFFT;
  float2* kf0 = Kf + (size_t)c0 * NFFT;
  float2* kf1 = kf0 + NFFT;
  int mt = (256 - t) & 255;
  #pragma unroll
  for (int k1 = 0; k1 < 16; ++k1){
    int k = t + (k1 << 8);
    int mk1 = (t == 0) ? ((16 - k1) & 15) : (15 - k1);
    float2 Zk = r[BR4[k1]];
    float2 Zm = S[P16(mt + (mk1 << 8))];
    float gar = 0.5f*(Zk.x + Zm.x), gai = 0.5f*(Zk.y - Zm.y);
    float gbr = 0.5f*(Zk.y + Zm.y), gbi = 0.5f*(Zm.x - Zk.x);
    kf0[k] = make_float2(gar*inv, gai*inv);
    kf1[k] = make_float2(gbr*inv, gbi*inv);
  }
}

// ===== 2-phase/K-tile 8-wave GEMM, 128x128 tile -> 64KB LDS -> 2 blocks/CU =====
__device__ __forceinline__ void gbar(){ __builtin_amdgcn_s_barrier(); }
__device__ __forceinline__ void lgk0(){
  asm volatile("s_waitcnt lgkmcnt(0)" ::: "memory");
  __builtin_amdgcn_sched_barrier(0);
}
template<int V>
__device__ __forceinline__ void waitvm(){
  if constexpr (V == 8) asm volatile("s_waitcnt vmcnt(8)" ::: "memory");
  else if constexpr (V == 4) asm volatile("s_waitcnt vmcnt(4)" ::: "memory");
  else asm volatile("s_waitcnt vmcnt(0)" ::: "memory");
  __builtin_amdgcn_sched_barrier(0);
}

template<int BM, int BN, bool OUT_BF16>
__global__ __launch_bounds__(512, 4) void k_gemm8(const u16* __restrict__ A, const u16* __restrict__ Bt,
                                                  const float* __restrict__ bias, void* __restrict__ Cout,
                                                  int M, int N, int K){
  constexpr int MR  = BM / 32;
  constexpr int NR  = BN / 64;
  constexpr int LA  = BM / 128;
  constexpr int LB  = BN / 128;
  constexpr int V   = 2 * (LA + LB);
  static_assert(LA * 128 == BM && LB * 128 == BN, "stage divisors");
  __shared__ __align__(16) u16 lds[2 * 64 * (BM + BN)];
  const int tid = threadIdx.x;
  const int lane = tid & 63, w = tid >> 6;
  const int wm = w >> 2, wn = w & 3;
  const int lr = lane & 15, lk8 = (lane >> 4) * 8;
  const int NT = K >> 6;

  // n-fast decomposition: each XCD owns an m-panel (A L2-resident, B via L3)
  const int NNT = N / BN;
  int nwg = gridDim.x;
  int swz = (blockIdx.x & 7) * (nwg >> 3) + (blockIdx.x >> 3);
  int m0 = (swz / NNT) * BM;
  int n0 = (swz % NNT) * BN;

  u16* baseA = lds;
  u16* baseB = lds + 2 * 64 * BM;

  auto stageA = [&](int kts, int db, int kh){
    int kc0 = (kts << 6) + kh * 32;
    u16* slab = baseA + db * (BM * 64) + kh * (BM * 32);
    #pragma unroll
    for (int q = 0; q < LA; ++q){
      int row = q * 128 + (tid >> 2);
      int cl = ((tid & 3) * 8) ^ (((row >> 1) & 3) << 3);
      async16(A + (size_t)(m0 + row) * K + kc0 + cl, slab + q * 4096 + (w << 9));
    }
  };
  auto stageB = [&](int kts, int db, int kh){
    int kc0 = (kts << 6) + kh * 32;
    u16* slab = baseB + db * (BN * 64) + kh * (BN * 32);
    #pragma unroll
    for (int q = 0; q < LB; ++q){
      int row = q * 128 + (tid >> 2);
      int cl = ((tid & 3) * 8) ^ (((row >> 1) & 3) << 3);
      async16(Bt + (size_t)(n0 + row) * K + kc0 + cl, slab + q * 4096 + (w << 9));
    }
  };

  f32x4 acc[MR][NR] = {};
  short8 af[MR], bf[NR];

  auto readA = [&](int db, int kh){
    const u16* base = baseA + db * (BM * 64) + kh * (BM * 32);
    #pragma unroll
    for (int i = 0; i < MR; ++i){
      int ar = wm * (BM / 2) + i * 16 + lr;
      af[i] = *(const short8*)&base[ar * 32 + (lk8 ^ (((ar >> 1) & 3) << 3))];
    }
  };
  auto readB = [&](int db, int kh){
    const u16* base = baseB + db * (BN * 64) + kh * (BN * 32);
    #pragma unroll
    for (int j = 0; j < NR; ++j){
      int br = wn * (BN / 4) + j * 16 + lr;
      bf[j] = *(const short8*)&base[br * 32 + (lk8 ^ (((br >> 1) & 3) << 3))];
    }
  };

#define MFMA_FULL                                                              \
  __builtin_amdgcn_s_setprio(1);                                               \
  _Pragma("unroll")                                                            \
  for (int i = 0; i < MR; ++i)                                                 \
    _Pragma("unroll")                                                          \
    for (int j = 0; j < NR; ++j)                                               \
      acc[i][j] = __builtin_amdgcn_mfma_f32_16x16x32_bf16(                     \
          af[i], bf[j], acc[i][j], 0, 0, 0);                                   \
  __builtin_amdgcn_s_setprio(0);

  // prologue: stage kt0 (both kh) + kt1 kh0
  stageA(0, 0, 0); stageB(0, 0, 0);
  stageA(0, 0, 1); stageB(0, 0, 1);
  stageA(1, 1, 0); stageB(1, 1, 0);
  waitvm<V>();
  gbar();

  for (int kt = 0; kt < NT; ++kt){
    int b = kt & 1, bn2 = b ^ 1;
    int t1 = (kt + 1 < NT) ? kt + 1 : 0;
    int t2 = (kt + 2 < NT) ? kt + 2 : 0;
    // phase 0 (kh0)
    readB(b, 0); readA(b, 0);
    stageA(t1, bn2, 1); stageB(t1, bn2, 1);
    gbar(); lgk0();
    MFMA_FULL
    waitvm<V>();
    gbar();
    // phase 1 (kh1)
    readB(b, 1); readA(b, 1);
    stageA(t2, b, 0); stageB(t2, b, 0);
    gbar(); lgk0();
    MFMA_FULL
    waitvm<V>();
    gbar();
  }
#undef MFMA_FULL

  waitvm<0>();
  gbar();
  if constexpr (OUT_BF16){
    constexpr int BST = BN + 8;
    u16* lbuf = lds;
    #pragma unroll
    for (int j = 0; j < NR; ++j){
      int col = wn * (BN / 4) + j * 16 + lr;
      float bv = bias[n0 + col];
      #pragma unroll
      for (int i = 0; i < MR; ++i){
        int rw = wm * (BM / 2) + i * 16 + (lane >> 4) * 4;
        #pragma unroll
        for (int r = 0; r < 4; ++r)
          lbuf[(rw + r) * BST + col] = f2bf(acc[i][j][r] + bv);
      }
    }
    gbar();
    constexpr int ROWCH = BN / 8;
    constexpr int CHUNKS = BM * ROWCH;
    #pragma unroll
    for (int q = 0; q < CHUNKS / 512; ++q){
      int c = tid + q * 512;
      int row = c / ROWCH, col8 = (c % ROWCH) * 8;
      f32x4 vv = *(const f32x4*)&lbuf[row * BST + col8];
      *(f32x4*)((u16*)Cout + (size_t)(m0 + row) * N + n0 + col8) = vv;
    }
  } else {
    constexpr int BSTF = BN + 4;
    float* lbuf = (float*)lds;
    constexpr int ROWCHF = BN / 4;
    constexpr int CHUNKSF = (BM / 2) * ROWCHF;
    #pragma unroll
    for (int p = 0; p < 2; ++p){
      if (wm == p){
        #pragma unroll
        for (int j = 0; j < NR; ++j){
          int col = wn * (BN / 4) + j * 16 + lr;
          float bv = bias[n0 + col];
          #pragma unroll
          for (int i = 0; i < MR; ++i){
            int rl = i * 16 + (lane >> 4) * 4;
            #pragma unroll
            for (int r = 0; r < 4; ++r)
              lbuf[(rl + r) * BSTF + col] = acc[i][j][r] + bv;
          }
        }
      }
      gbar();
      #pragma unroll
      for (int q = 0; q < CHUNKSF / 512; ++q){
        int c = tid + q * 512;
        int row = c / ROWCHF, col4 = (c % ROWCHF) * 4;
        f32x4 vv = *(const f32x4*)&lbuf[row * BSTF + col4];
        *(f32x4*)((float*)Cout + (size_t)(m0 + p * (BM / 2) + row) * N + n0 + col4) = vv;
      }
      gbar();
    }
  }
}

// ---------------- short conv + gate + transpose to (b,d,l), vectorized ----------------
__device__ __forceinline__ int ogcol(int c, int t){ return c * 136 + (t ^ (((c >> 3) & 7) << 4)); }

__global__ __launch_bounds__(256) void k_shortconv(const u16* __restrict__ up, const float* __restrict__ sw,
                            const float* __restrict__ sb,
                            u16* __restrict__ gOut, u16* __restrict__ x0Out){
  __shared__ u16 og[2][64 * 136];
  const int t0 = blockIdx.x * 128;
  const int c0 = blockIdx.y * 64;
  const int b  = blockIdx.z;
  const int tid = threadIdx.x;
  const int c8 = (tid & 7) * 8;
  const int tt = (tid >> 3) * 4;
  const int cg = c0 + c8;

  auto conv_group = [&](int g2, float out[8][4]){
    const f32x4* wp = (const f32x4*)(sw + (size_t)(g2 * DM + cg) * 3);
    f32x4 w03 = wp[0], w47 = wp[1], w8b = wp[2], wcf = wp[3], wgj = wp[4], wkn = wp[5];
    float wv[24];
    #pragma unroll
    for (int x = 0; x < 4; ++x){ wv[x] = w03[x]; wv[4+x] = w47[x]; wv[8+x] = w8b[x];
                                 wv[12+x] = wcf[x]; wv[16+x] = wgj[x]; wv[20+x] = wkn[x]; }
    const f32x4* bp = (const f32x4*)(sb + g2 * DM + cg);
    f32x4 b03 = bp[0], b47 = bp[1];
    float bv[8];
    #pragma unroll
    for (int x = 0; x < 4; ++x){ bv[x] = b03[x]; bv[4+x] = b47[x]; }
    const u16* base = up + ((size_t)(b * L_SEQ + t0 + tt - 2)) * TW + g2 * DM + cg;
    short8 rows[6];
    #pragma unroll
    for (int r = 0; r < 6; ++r){
      int t = t0 + tt - 2 + r;
      if (t >= 0) rows[r] = *(const short8*)(base + (size_t)r * TW);
      else rows[r] = (short8)0;
    }
    #pragma unroll
    for (int j = 0; j < 8; ++j){
      float w0 = wv[j*3], w1 = wv[j*3+1], w2 = wv[j*3+2], bb = bv[j];
      #pragma unroll
      for (int q = 0; q < 4; ++q){
        out[j][q] = w0 * bf2f((u16)rows[q][j]) + w1 * bf2f((u16)rows[q+1][j])
                  + w2 * bf2f((u16)rows[q+2][j]) + bb;
      }
    }
  };

  float x1v[8][4], gv[8][4], x0v[8][4];
  conv_group(1, x1v);
  conv_group(2, gv);
  #pragma unroll
  for (int j = 0; j < 8; ++j)
    #pragma unroll
    for (int q = 0; q < 4; ++q) gv[j][q] *= x1v[j][q];
  conv_group(0, x0v);

  #pragma unroll
  for (int j = 0; j < 8; ++j){
    short4x px, pg;
    #pragma unroll
    for (int q = 0; q < 4; ++q){ px[q] = (short)f2bf(x0v[j][q]); pg[q] = (short)f2bf(gv[j][q]); }
    int col = ogcol(c8 + j, tt);
    *(short4x*)&og[0][col] = px;
    *(short4x*)&og[1][col] = pg;
  }
  __syncthreads();

  #pragma unroll
  for (int q = 0; q < 4; ++q){
    int ch = tid + q * 256;
    int c = ch >> 4, t8 = (ch & 15) * 8;
    size_t gb = ((size_t)(b * DM + c0 + c)) * L_SEQ + t0 + t8;
    f32x4 v0 = *(const f32x4*)&og[0][ogcol(c, t8)];
    *(f32x4*)(x0Out + gb) = v0;
    f32x4 v1 = *(const f32x4*)&og[1][ogcol(c, t8)];
    *(f32x4*)(gOut + gb) = v1;
  }
}

// ---- FFT conv: per-batch (grid DM/2 x BATCH), twiddles cached in registers ----
__global__ __launch_bounds__(256) void k_fftconv(const u16* __restrict__ g, const u16* __restrict__ x0,
                          const float2* __restrict__ Kf, const float* __restrict__ fbias,
                          u16* __restrict__ z){
  int c0 = blockIdx.x * 2;
  int b = blockIdx.y;
  int t = threadIdx.x;
  __shared__ float2 S[4352];
  const int n1 = t & 15, hi = t >> 4;
  // two twiddle families cover all 6 stages (inverse = conjugate)
  float t1c[16], t1s[16], t2c[16], t2s[16];
  #pragma unroll
  for (int k = 0; k < 16; ++k){
    sincos_rev(-(float)(hi * k) * (1.0f/256.0f), t1s[k], t1c[k]);
    sincos_rev(-(float)(n1 * (hi + 16*k)) * (1.0f/4096.0f), t2s[k], t2c[k]);
  }
  const float2* kf0 = Kf + (size_t)c0 * NFFT;
  const float2* kf1 = kf0 + NFFT;
  const float fb0 = fbias[c0], fb1 = fbias[c0+1];
  const int mt = (256 - t) & 255;
  const size_t row0 = ((size_t)(b * DM + c0)) * L_SEQ;
  const size_t row1 = row0 + L_SEQ;

  float2 r[16];
  #pragma unroll
  for (int n3 = 0; n3 < 8; ++n3){
    int n = t + (n3 << 8);
    r[n3] = make_float2(bf2f(g[row0 + n]), bf2f(g[row1 + n]));
    r[n3 + 8] = make_float2(0.f, 0.f);
  }
  fft16<1>(r);
  #pragma unroll
  for (int k3 = 0; k3 < 16; ++k3)
    S[P16(k3*256 + hi*16 + n1)] = cmulf(r[BR4[k3]], t1c[k3], t1s[k3]);
  __syncthreads();
  #pragma unroll
  for (int n2 = 0; n2 < 16; ++n2)
    r[n2] = S[P16(hi*256 + n2*16 + n1)];
  __syncthreads();
  fft16<1>(r);
  #pragma unroll
  for (int k2 = 0; k2 < 16; ++k2)
    S[P16(k2*256 + hi*16 + n1)] = cmulf(r[BR4[k2]], t2c[k2], t2s[k2]);
  __syncthreads();
  #pragma unroll
  for (int m = 0; m < 16; ++m)
    r[m] = S[P16(hi*256 + n1*16 + m)];
  __syncthreads();
  fft16<1>(r);
  #pragma unroll
  for (int k1 = 0; k1 < 16; ++k1)
    S[P16(t + (k1 << 8))] = r[BR4[k1]];
  __syncthreads();
  float2 y[16];
  #pragma unroll
  for (int k1 = 0; k1 < 16; ++k1){
    int k = t + (k1 << 8);
    int mk1 = (t == 0) ? ((16 - k1) & 15) : (15 - k1);
    float2 Zk = r[BR4[k1]];
    float2 Zm = S[P16(mt + (mk1 << 8))];
    float2 K0 = kf0[k], K1 = kf1[k];
    float gar = 0.5f*(Zk.x + Zm.x), gai = 0.5f*(Zk.y - Zm.y);
    float gbr = 0.5f*(Zk.y + Zm.y), gbi = 0.5f*(Zm.x - Zk.x);
    float yar = gar*K0.x - gai*K0.y, yai = gar*K0.y + gai*K0.x;
    float ybr = gbr*K1.x - gbi*K1.y, ybi = gbr*K1.y + gbi*K1.x;
    y[k1] = make_float2(yar - ybi, yai + ybr);
  }
  fft16<-1>(y);
  __syncthreads();
  #pragma unroll
  for (int n3 = 0; n3 < 16; ++n3)
    S[P16(n3*256 + hi*16 + n1)] = cmulf(y[BR4[n3]], t1c[n3], -t1s[n3]);
  __syncthreads();
  #pragma unroll
  for (int m2 = 0; m2 < 16; ++m2)
    r[m2] = S[P16(hi*256 + m2*16 + n1)];
  __syncthreads();
  fft16<-1>(r);
  #pragma unroll
  for (int nn2 = 0; nn2 < 16; ++nn2)
    S[P16(nn2*256 + hi*16 + n1)] = cmulf(r[BR4[nn2]], t2c[nn2], -t2s[nn2]);
  __syncthreads();
  #pragma unroll
  for (int m = 0; m < 16; ++m)
    r[m] = S[P16(hi*256 + n1*16 + m)];
  fft16<-1>(r);
  #pragma unroll
  for (int q = 0; q < 8; ++q){
    int n = t + (q << 8);
    float2 val = r[BR4[q]];
    float g0 = bf2f(g[row0 + n]), g1 = bf2f(g[row1 + n]);
    float x00 = bf2f(x0[row0 + n]), x01 = bf2f(x0[row1 + n]);
    z[row0 + n] = f2bf((val.x + g0*fb0) * x00);
    z[row1 + n] = f2bf((val.y + g1*fb1) * x01);
  }
}

// ---------------- transpose z: (b,d,l) bf16 -> (b,l,d) bf16 ----------------
__global__ void k_transpose_z(const u16* __restrict__ zin, u16* __restrict__ zout){
  __shared__ u16 tile[32][33];
  int l0 = blockIdx.x * 32, d0 = blockIdx.y * 32, b = blockIdx.z;
  int x = threadIdx.x, y = threadIdx.y;
  for (int i = 0; i < 4; ++i){
    int d = d0 + y + i*8;
    tile[y + i*8][x] = zin[((size_t)(b * DM + d)) * L_SEQ + l0 + x];
  }
  __syncthreads();
  for (int i = 0; i < 4; ++i){
    int l = l0 + y + i*8;
    zout[((size_t)(b * L_SEQ + l)) * DM + d0 + x] = tile[x][y + i*8];
  }
}

extern "C" void kernel_launch(void* const* d_in, const int* in_sizes, int n_in,
                              void* d_out, int out_size, void* d_ws, size_t ws_size,
                              hipStream_t stream){
  (void)in_sizes; (void)n_in; (void)out_size; (void)ws_size;
  const float* u       = (const float*)d_in[0];
  const float* in_w    = (const float*)d_in[1];
  const float* in_b    = (const float*)d_in[2];
  const float* short_w = (const float*)d_in[3];
  const float* short_b = (const float*)d_in[4];
  const float* w0 = (const float*)d_in[5];
  const float* b0 = (const float*)d_in[6];
  const float* f0 = (const float*)d_in[7];
  const float* w1 = (const float*)d_in[8];
  const float* b1 = (const float*)d_in[9];
  const float* f1 = (const float*)d_in[10];
  const float* w2 = (const float*)d_in[11];
  const float* b2 = (const float*)d_in[12];
  const float* f2 = (const float*)d_in[13];
  const float* w3 = (const float*)d_in[14];
  const float* fbias = (const float*)d_in[15];
  const float* out_w = (const float*)d_in[16];
  const float* out_b = (const float*)d_in[17];
  float* out = (float*)d_out;

  char* ws = (char*)d_ws;
  size_t off = 0;
  auto alloc = [&](size_t bytes)->void*{
    void* p = ws + off; off += (bytes + 255) & ~(size_t)255; return p;
  };
  const int M = BATCH * L_SEQ; // 8192
  u16*   u_bf  = (u16*)  alloc((size_t)M * DM * 2);       // later reused as z
  u16*   inwT  = (u16*)  alloc((size_t)TW * DM * 2);
  u16*   outwT = (u16*)  alloc((size_t)DM * DM * 2);
  float* H2T   = (float*)alloc((size_t)L_SEQ * 64 * 4);
  float2* Kf   = (float2*)alloc((size_t)DM * NFFT * 8);
  u16*   up    = (u16*)  alloc((size_t)M * TW * 2);       // later reused as zT
  u16*   gbuf  = (u16*)  alloc((size_t)BATCH * DM * L_SEQ * 2);
  u16*   x0buf = (u16*)  alloc((size_t)BATCH * DM * L_SEQ * 2);
  u16*   z  = u_bf;   // alias: u_bf dead after gemm1
  u16*   zT = up;     // alias: up dead after shortconv

  k_convert_u<<<2048, 256, 0, stream>>>((const float4*)u, u_bf, (M * DM) / 4);
  k_transpose_w<<<dim3(TW/32, DM/32), dim3(32, 8), 0, stream>>>(in_w, inwT, DM, TW);
  k_transpose_w<<<dim3(DM/32, DM/32), dim3(32, 8), 0, stream>>>(out_w, outwT, DM, DM);
  k_filter_h2<<<L_SEQ, 64, 0, stream>>>(w0, b0, f0, w1, b1, f1, w2, b2, f2, H2T);
  k_filter_fft16<<<DM/2, 256, 0, stream>>>(H2T, w3, Kf);
  k_gemm8<128, 128, true><<<dim3((M/128)*(TW/128)), 512, 0, stream>>>(u_bf, inwT, in_b, up, M, TW, DM);
  k_shortconv<<<dim3(L_SEQ/128, DM/64, BATCH), 256, 0, stream>>>(up, short_w, short_b, gbuf, x0buf);
  k_fftconv<<<dim3(DM/2, BATCH), 256, 0, stream>>>(gbuf, x0buf, Kf, fbias, z);
  k_transpose_z<<<dim3(L_SEQ/32, DM/32, BATCH), dim3(32, 8), 0, stream>>>(z, zT);
  k_gemm8<128, 128, false><<<dim3((M/128)*(DM/128)), 512, 0, stream>>>(zT, outwT, out_b, out, M, DM, DM);
}

// Round 13
// 190.824 us; speedup vs baseline: 1.2424x; 1.0340x over previous
//
#include <hip/hip_runtime.h>
#include <stdint.h>

typedef unsigned short u16;
typedef __attribute__((ext_vector_type(8))) short short8;
typedef __attribute__((ext_vector_type(4))) short short4x;
typedef __attribute__((ext_vector_type(4))) float f32x4;

#define PI_F 3.14159265358979323846f
#define L_SEQ 2048
#define NFFT 4096
#define DM 1024
#define TW 3072
#define BATCH 4

__device__ __forceinline__ u16 f2bf(float f){
  union { float f; uint32_t u; } v; v.f = f;
  uint32_t r = v.u + 0x7fffu + ((v.u >> 16) & 1u);
  return (u16)(r >> 16);
}
__device__ __forceinline__ float bf2f(u16 h){
  union { uint32_t u; float f; } v; v.u = ((uint32_t)h) << 16;
  return v.f;
}

__device__ __forceinline__ void async16(const void* g, void* l){
  __builtin_amdgcn_global_load_lds(
      (const __attribute__((address_space(1))) void*)g,
      (__attribute__((address_space(3))) void*)l, 16, 0, 0);
}

// hardware sin/cos, input in REVOLUTIONS (angle = 2*pi*rev)
__device__ __forceinline__ void sincos_rev(float rev, float& sn, float& cs){
  asm("v_sin_f32 %0, %1" : "=v"(sn) : "v"(rev));
  asm("v_cos_f32 %0, %1" : "=v"(cs) : "v"(rev));
}

__device__ __forceinline__ float2 cmulf(float2 a, float c, float s){
  return make_float2(a.x*c - a.y*s, a.x*s + a.y*c);
}

__device__ __forceinline__ int P16(int i){ return i + (i >> 4); }

__device__ static constexpr int BR4[16] = {0,8,4,12,2,10,6,14,1,9,5,13,3,11,7,15};

template<int SGN>
__device__ __forceinline__ void fft16(float2* a){
  const float s = (float)SGN;
  static constexpr float tc[8]  = {1.f, 0.92387953f, 0.70710678f, 0.38268343f,
                                   0.f, -0.38268343f, -0.70710678f, -0.92387953f};
  static constexpr float ts_[8] = {0.f, -0.38268343f, -0.70710678f, -0.92387953f,
                                   -1.f, -0.92387953f, -0.70710678f, -0.38268343f};
  #pragma unroll
  for (int j = 0; j < 8; ++j){
    float2 u = a[j], v = a[j+8];
    float2 d = make_float2(u.x - v.x, u.y - v.y);
    a[j] = make_float2(u.x + v.x, u.y + v.y);
    a[j+8] = cmulf(d, tc[j], s*ts_[j]);
  }
  #pragma unroll
  for (int g = 0; g < 2; ++g){
    int b = g*8;
    #pragma unroll
    for (int j = 0; j < 4; ++j){
      float2 u = a[b+j], v = a[b+j+4];
      float2 d = make_float2(u.x - v.x, u.y - v.y);
      a[b+j] = make_float2(u.x + v.x, u.y + v.y);
      a[b+j+4] = cmulf(d, tc[2*j], s*ts_[2*j]);
    }
  }
  #pragma unroll
  for (int g = 0; g < 4; ++g){
    int b = g*4;
    #pragma unroll
    for (int j = 0; j < 2; ++j){
      float2 u = a[b+j], v = a[b+j+2];
      float2 d = make_float2(u.x - v.x, u.y - v.y);
      a[b+j] = make_float2(u.x + v.x, u.y + v.y);
      a[b+j+2] = (j == 0) ? d : cmulf(d, 0.f, -s);
    }
  }
  #pragma unroll
  for (int g = 0; g < 8; ++g){
    int b = g*2;
    float2 u = a[b], v = a[b+1];
    a[b] = make_float2(u.x + v.x, u.y + v.y);
    a[b+1] = make_float2(u.x - v.x, u.y - v.y);
  }
}

// ---------------- convert u (fp32 -> bf16), vectorized ----------------
__global__ void k_convert_u(const float4* __restrict__ in, u16* __restrict__ outp, int n4){
  int idx = blockIdx.x * blockDim.x + threadIdx.x;
  int stride = gridDim.x * blockDim.x;
  for (int i = idx; i < n4; i += stride){
    float4 v = in[i];
    u16 r0 = f2bf(v.x), r1 = f2bf(v.y), r2 = f2bf(v.z), r3 = f2bf(v.w);
    u16* o = outp + (size_t)i * 4;
    o[0] = r0; o[1] = r1; o[2] = r2; o[3] = r3;
  }
}

// ---------------- transpose weight fp32 (K,N) -> bf16 (N,K) ----------------
__global__ void k_transpose_w(const float* __restrict__ in, u16* __restrict__ outp, int K, int N){
  __shared__ float tile[32][33];
  int n0 = blockIdx.x * 32, k0 = blockIdx.y * 32;
  int x = threadIdx.x, y = threadIdx.y;
  for (int i = 0; i < 4; ++i)
    tile[y + i*8][x] = in[(size_t)(k0 + y + i*8) * N + n0 + x];
  __syncthreads();
  for (int i = 0; i < 4; ++i)
    outp[(size_t)(n0 + y + i*8) * K + k0 + x] = f2bf(tile[x][y + i*8]);
}

// ---------------- filter MLP: H2T (64 x 2048, TRANSPOSED) ----------------
__global__ void k_filter_h2(const float* __restrict__ w0, const float* __restrict__ b0, const float* __restrict__ f0,
                            const float* __restrict__ w1, const float* __restrict__ b1, const float* __restrict__ f1,
                            const float* __restrict__ w2, const float* __restrict__ b2, const float* __restrict__ f2,
                            float* __restrict__ H2T){
  int t = blockIdx.x;
  int j = threadIdx.x; // 0..63
  float tn = t * (1.0f / 2047.0f);
  float ph = 1e-4f * 2.0f * PI_F * (float)t * (1.0f / 2048.0f);
  float z0 = tn, z1 = cosf(ph), z2 = -sinf(ph);
  __shared__ float hs[64];
  float pre = z0 * w0[j] + z1 * w0[64 + j] + z2 * w0[128 + j] + b0[j];
  float h = sinf(f0[j] * pre);
  hs[j] = h;
  __syncthreads();
  float acc = b1[j];
  for (int i = 0; i < 64; ++i) acc += hs[i] * w1[i*64 + j];
  h = sinf(f1[j] * acc);
  __syncthreads();
  hs[j] = h;
  __syncthreads();
  acc = b2[j];
  for (int i = 0; i < 64; ++i) acc += hs[i] * w2[i*64 + j];
  h = sinf(f2[j] * acc);
  H2T[j * L_SEQ + t] = h;
}

// ---------------- filter spectra: radix-16 register FFT, 2 channels packed ----
__global__ __launch_bounds__(256) void k_filter_fft16(const float* __restrict__ H2T,
                                                      const float* __restrict__ w3,
                                                      float2* __restrict__ Kf){
  int c0 = blockIdx.x * 2;
  int t = threadIdx.x;
  __shared__ float2 S[4352];
  __shared__ float wcol[2][64];
  if (t < 64){ wcol[0][t] = w3[t * DM + c0]; wcol[1][t] = w3[t * DM + c0 + 1]; }
  __syncthreads();
  const int n1 = t & 15, hi = t >> 4;
  float absd0 = 3.070113457325394f + 12.280453829301576f * ((float)c0 * (1.0f / 1023.0f));
  float absd1 = 3.070113457325394f + 12.280453829301576f * ((float)(c0+1) * (1.0f / 1023.0f));
  float sa[8] = {0,0,0,0,0,0,0,0}, sb[8] = {0,0,0,0,0,0,0,0};
  for (int j = 0; j < 64; ++j){
    float wa = wcol[0][j], wb = wcol[1][j];
    const float* hrow = H2T + j * L_SEQ + t;
    #pragma unroll
    for (int n3 = 0; n3 < 8; ++n3){
      float h = hrow[n3 << 8];
      sa[n3] += h * wa; sb[n3] += h * wb;
    }
  }
  float2 r[16];
  #pragma unroll
  for (int n3 = 0; n3 < 8; ++n3){
    int n = t + (n3 << 8);
    float tn = (float)n * (1.0f / 2047.0f);
    r[n3] = make_float2(sa[n3] * __expf(-tn * absd0), sb[n3] * __expf(-tn * absd1));
    r[n3 + 8] = make_float2(0.f, 0.f);
  }
  fft16<1>(r);
  #pragma unroll
  for (int k3 = 0; k3 < 16; ++k3){
    float sn, cs; sincos_rev(-(float)(hi * k3) * (1.0f/256.0f), sn, cs);
    S[P16(k3*256 + hi*16 + n1)] = cmulf(r[BR4[k3]], cs, sn);
  }
  __syncthreads();
  #pragma unroll
  for (int n2 = 0; n2 < 16; ++n2)
    r[n2] = S[P16(hi*256 + n2*16 + n1)];
  __syncthreads();
  fft16<1>(r);
  #pragma unroll
  for (int k2 = 0; k2 < 16; ++k2){
    float sn, cs; sincos_rev(-(float)(n1 * (hi + 16*k2)) * (1.0f/4096.0f), sn, cs);
    S[P16(k2*256 + hi*16 + n1)] = cmulf(r[BR4[k2]], cs, sn);
  }
  __syncthreads();
  #pragma unroll
  for (int m = 0; m < 16; ++m)
    r[m] = S[P16(hi*256 + n1*16 + m)];
  __syncthreads();
  fft16<1>(r);
  #pragma unroll
  for (int k1 = 0; k1 < 16; ++k1)
    S[P16(t + (k1 << 8))] = r[BR4[k1]];
  __syncthreads();
  const float inv = 1.0f / (float)NFFT;
  float2* kf0 = Kf + (size_t)c0 * NFFT;
  float2* kf1 = kf0 + NFFT;
  int mt = (256 - t) & 255;
  #pragma unroll
  for (int k1 = 0; k1 < 16; ++k1){
    int k = t + (k1 << 8);
    int mk1 = (t == 0) ? ((16 - k1) & 15) : (15 - k1);
    float2 Zk = r[BR4[k1]];
    float2 Zm = S[P16(mt + (mk1 << 8))];
    float gar = 0.5f*(Zk.x + Zm.x), gai = 0.5f*(Zk.y - Zm.y);
    float gbr = 0.5f*(Zk.y + Zm.y), gbi = 0.5f*(Zm.x - Zk.x);
    kf0[k] = make_float2(gar*inv, gai*inv);
    kf1[k] = make_float2(gbr*inv, gbi*inv);
  }
}

// ===== R8-exact 2-phase/K-tile 8-wave GEMM (best measured: 65.1us gemm1) =====
__device__ __forceinline__ void gbar(){ __builtin_amdgcn_s_barrier(); }
__device__ __forceinline__ void lgk0(){
  asm volatile("s_waitcnt lgkmcnt(0)" ::: "memory");
  __builtin_amdgcn_sched_barrier(0);
}
template<int V>
__device__ __forceinline__ void waitvm(){
  if constexpr (V == 8) asm volatile("s_waitcnt vmcnt(8)" ::: "memory");
  else if constexpr (V == 6) asm volatile("s_waitcnt vmcnt(6)" ::: "memory");
  else asm volatile("s_waitcnt vmcnt(0)" ::: "memory");
  __builtin_amdgcn_sched_barrier(0);
}

template<int BM, int BN, bool OUT_BF16>
__global__ __launch_bounds__(512, 2) void k_gemm8(const u16* __restrict__ A, const u16* __restrict__ Bt,
                                                  const float* __restrict__ bias, void* __restrict__ Cout,
                                                  int M, int N, int K){
  constexpr int MR  = BM / 32;
  constexpr int NR  = BN / 64;
  constexpr int LA  = BM / 128;
  constexpr int LB  = BN / 128;
  constexpr int V   = 2 * (LA + LB);
  static_assert(LA * 128 == BM && LB * 128 == BN, "stage divisors");
  __shared__ __align__(16) u16 lds[2 * 64 * (BM + BN)];
  const int tid = threadIdx.x;
  const int lane = tid & 63, w = tid >> 6;
  const int wm = w >> 2, wn = w & 3;
  const int lr = lane & 15, lk8 = (lane >> 4) * 8;
  const int NT = K >> 6;

  // n-fast decomposition: each XCD owns an m-panel (A L2-resident, B via L3)
  const int NNT = N / BN;
  int nwg = gridDim.x;
  int swz = (blockIdx.x & 7) * (nwg >> 3) + (blockIdx.x >> 3);
  int m0 = (swz / NNT) * BM;
  int n0 = (swz % NNT) * BN;

  u16* baseA = lds;
  u16* baseB = lds + 2 * 64 * BM;

  auto stageA = [&](int kts, int db, int kh){
    int kc0 = (kts << 6) + kh * 32;
    u16* slab = baseA + db * (BM * 64) + kh * (BM * 32);
    #pragma unroll
    for (int q = 0; q < LA; ++q){
      int row = q * 128 + (tid >> 2);
      int cl = ((tid & 3) * 8) ^ (((row >> 1) & 3) << 3);
      async16(A + (size_t)(m0 + row) * K + kc0 + cl, slab + q * 4096 + (w << 9));
    }
  };
  auto stageB = [&](int kts, int db, int kh){
    int kc0 = (kts << 6) + kh * 32;
    u16* slab = baseB + db * (BN * 64) + kh * (BN * 32);
    #pragma unroll
    for (int q = 0; q < LB; ++q){
      int row = q * 128 + (tid >> 2);
      int cl = ((tid & 3) * 8) ^ (((row >> 1) & 3) << 3);
      async16(Bt + (size_t)(n0 + row) * K + kc0 + cl, slab + q * 4096 + (w << 9));
    }
  };

  f32x4 acc[MR][NR] = {};
  short8 af[MR], bf[NR];

  auto readA = [&](int db, int kh){
    const u16* base = baseA + db * (BM * 64) + kh * (BM * 32);
    #pragma unroll
    for (int i = 0; i < MR; ++i){
      int ar = wm * (BM / 2) + i * 16 + lr;
      af[i] = *(const short8*)&base[ar * 32 + (lk8 ^ (((ar >> 1) & 3) << 3))];
    }
  };
  auto readB = [&](int db, int kh){
    const u16* base = baseB + db * (BN * 64) + kh * (BN * 32);
    #pragma unroll
    for (int j = 0; j < NR; ++j){
      int br = wn * (BN / 4) + j * 16 + lr;
      bf[j] = *(const short8*)&base[br * 32 + (lk8 ^ (((br >> 1) & 3) << 3))];
    }
  };

#define MFMA_FULL                                                              \
  __builtin_amdgcn_s_setprio(1);                                               \
  _Pragma("unroll")                                                            \
  for (int i = 0; i < MR; ++i)                                                 \
    _Pragma("unroll")                                                          \
    for (int j = 0; j < NR; ++j)                                               \
      acc[i][j] = __builtin_amdgcn_mfma_f32_16x16x32_bf16(                     \
          af[i], bf[j], acc[i][j], 0, 0, 0);                                   \
  __builtin_amdgcn_s_setprio(0);

  // prologue: stage kt0 (both kh) + kt1 kh0
  stageA(0, 0, 0); stageB(0, 0, 0);
  stageA(0, 0, 1); stageB(0, 0, 1);
  stageA(1, 1, 0); stageB(1, 1, 0);
  waitvm<V>();
  gbar();

  for (int kt = 0; kt < NT; ++kt){
    int b = kt & 1, bn2 = b ^ 1;
    int t1 = (kt + 1 < NT) ? kt + 1 : 0;
    int t2 = (kt + 2 < NT) ? kt + 2 : 0;
    // phase 0 (kh0)
    readB(b, 0); readA(b, 0);
    stageA(t1, bn2, 1); stageB(t1, bn2, 1);
    gbar(); lgk0();
    MFMA_FULL
    waitvm<V>();
    gbar();
    // phase 1 (kh1)
    readB(b, 1); readA(b, 1);
    stageA(t2, b, 0); stageB(t2, b, 0);
    gbar(); lgk0();
    MFMA_FULL
    waitvm<V>();
    gbar();
  }
#undef MFMA_FULL

  waitvm<0>();
  gbar();
  if constexpr (OUT_BF16){
    constexpr int BST = BN + 8;
    u16* lbuf = lds;
    #pragma unroll
    for (int j = 0; j < NR; ++j){
      int col = wn * (BN / 4) + j * 16 + lr;
      float bv = bias[n0 + col];
      #pragma unroll
      for (int i = 0; i < MR; ++i){
        int rw = wm * (BM / 2) + i * 16 + (lane >> 4) * 4;
        #pragma unroll
        for (int r = 0; r < 4; ++r)
          lbuf[(rw + r) * BST + col] = f2bf(acc[i][j][r] + bv);
      }
    }
    gbar();
    constexpr int ROWCH = BN / 8;
    constexpr int CHUNKS = BM * ROWCH;
    #pragma unroll
    for (int q = 0; q < CHUNKS / 512; ++q){
      int c = tid + q * 512;
      int row = c / ROWCH, col8 = (c % ROWCH) * 8;
      f32x4 vv = *(const f32x4*)&lbuf[row * BST + col8];
      *(f32x4*)((u16*)Cout + (size_t)(m0 + row) * N + n0 + col8) = vv;
    }
  } else {
    constexpr int BSTF = BN + 4;
    float* lbuf = (float*)lds;
    constexpr int ROWCHF = BN / 4;
    constexpr int CHUNKSF = (BM / 2) * ROWCHF;
    #pragma unroll
    for (int p = 0; p < 2; ++p){
      if (wm == p){
        #pragma unroll
        for (int j = 0; j < NR; ++j){
          int col = wn * (BN / 4) + j * 16 + lr;
          float bv = bias[n0 + col];
          #pragma unroll
          for (int i = 0; i < MR; ++i){
            int rl = i * 16 + (lane >> 4) * 4;
            #pragma unroll
            for (int r = 0; r < 4; ++r)
              lbuf[(rl + r) * BSTF + col] = acc[i][j][r] + bv;
          }
        }
      }
      gbar();
      #pragma unroll
      for (int q = 0; q < CHUNKSF / 512; ++q){
        int c = tid + q * 512;
        int row = c / ROWCHF, col4 = (c % ROWCHF) * 4;
        f32x4 vv = *(const f32x4*)&lbuf[row * BSTF + col4];
        *(f32x4*)((float*)Cout + (size_t)(m0 + p * (BM / 2) + row) * N + n0 + col4) = vv;
      }
      gbar();
    }
  }
}

// ---------------- short conv + gate + transpose to (b,d,l), vectorized ----------------
__device__ __forceinline__ int ogcol(int c, int t){ return c * 136 + (t ^ (((c >> 3) & 7) << 4)); }

__global__ __launch_bounds__(256) void k_shortconv(const u16* __restrict__ up, const float* __restrict__ sw,
                            const float* __restrict__ sb,
                            u16* __restrict__ gOut, u16* __restrict__ x0Out){
  __shared__ u16 og[2][64 * 136];
  const int t0 = blockIdx.x * 128;
  const int c0 = blockIdx.y * 64;
  const int b  = blockIdx.z;
  const int tid = threadIdx.x;
  const int c8 = (tid & 7) * 8;
  const int tt = (tid >> 3) * 4;
  const int cg = c0 + c8;

  auto conv_group = [&](int g2, float out[8][4]){
    const f32x4* wp = (const f32x4*)(sw + (size_t)(g2 * DM + cg) * 3);
    f32x4 w03 = wp[0], w47 = wp[1], w8b = wp[2], wcf = wp[3], wgj = wp[4], wkn = wp[5];
    float wv[24];
    #pragma unroll
    for (int x = 0; x < 4; ++x){ wv[x] = w03[x]; wv[4+x] = w47[x]; wv[8+x] = w8b[x];
                                 wv[12+x] = wcf[x]; wv[16+x] = wgj[x]; wv[20+x] = wkn[x]; }
    const f32x4* bp = (const f32x4*)(sb + g2 * DM + cg);
    f32x4 b03 = bp[0], b47 = bp[1];
    float bv[8];
    #pragma unroll
    for (int x = 0; x < 4; ++x){ bv[x] = b03[x]; bv[4+x] = b47[x]; }
    const u16* base = up + ((size_t)(b * L_SEQ + t0 + tt - 2)) * TW + g2 * DM + cg;
    short8 rows[6];
    #pragma unroll
    for (int r = 0; r < 6; ++r){
      int t = t0 + tt - 2 + r;
      if (t >= 0) rows[r] = *(const short8*)(base + (size_t)r * TW);
      else rows[r] = (short8)0;
    }
    #pragma unroll
    for (int j = 0; j < 8; ++j){
      float w0 = wv[j*3], w1 = wv[j*3+1], w2 = wv[j*3+2], bb = bv[j];
      #pragma unroll
      for (int q = 0; q < 4; ++q){
        out[j][q] = w0 * bf2f((u16)rows[q][j]) + w1 * bf2f((u16)rows[q+1][j])
                  + w2 * bf2f((u16)rows[q+2][j]) + bb;
      }
    }
  };

  float x1v[8][4], gv[8][4], x0v[8][4];
  conv_group(1, x1v);
  conv_group(2, gv);
  #pragma unroll
  for (int j = 0; j < 8; ++j)
    #pragma unroll
    for (int q = 0; q < 4; ++q) gv[j][q] *= x1v[j][q];
  conv_group(0, x0v);

  #pragma unroll
  for (int j = 0; j < 8; ++j){
    short4x px, pg;
    #pragma unroll
    for (int q = 0; q < 4; ++q){ px[q] = (short)f2bf(x0v[j][q]); pg[q] = (short)f2bf(gv[j][q]); }
    int col = ogcol(c8 + j, tt);
    *(short4x*)&og[0][col] = px;
    *(short4x*)&og[1][col] = pg;
  }
  __syncthreads();

  #pragma unroll
  for (int q = 0; q < 4; ++q){
    int ch = tid + q * 256;
    int c = ch >> 4, t8 = (ch & 15) * 8;
    size_t gb = ((size_t)(b * DM + c0 + c)) * L_SEQ + t0 + t8;
    f32x4 v0 = *(const f32x4*)&og[0][ogcol(c, t8)];
    *(f32x4*)(x0Out + gb) = v0;
    f32x4 v1 = *(const f32x4*)&og[1][ogcol(c, t8)];
    *(f32x4*)(gOut + gb) = v1;
  }
}

// ---- FFT conv: per-batch (grid DM/2 x BATCH), twiddles cached in registers ----
__global__ __launch_bounds__(256) void k_fftconv(const u16* __restrict__ g, const u16* __restrict__ x0,
                          const float2* __restrict__ Kf, const float* __restrict__ fbias,
                          u16* __restrict__ z){
  int c0 = blockIdx.x * 2;
  int b = blockIdx.y;
  int t = threadIdx.x;
  __shared__ float2 S[4352];
  const int n1 = t & 15, hi = t >> 4;
  float t1c[16], t1s[16], t2c[16], t2s[16];
  #pragma unroll
  for (int k = 0; k < 16; ++k){
    sincos_rev(-(float)(hi * k) * (1.0f/256.0f), t1s[k], t1c[k]);
    sincos_rev(-(float)(n1 * (hi + 16*k)) * (1.0f/4096.0f), t2s[k], t2c[k]);
  }
  const float2* kf0 = Kf + (size_t)c0 * NFFT;
  const float2* kf1 = kf0 + NFFT;
  const float fb0 = fbias[c0], fb1 = fbias[c0+1];
  const int mt = (256 - t) & 255;
  const size_t row0 = ((size_t)(b * DM + c0)) * L_SEQ;
  const size_t row1 = row0 + L_SEQ;

  float2 r[16];
  #pragma unroll
  for (int n3 = 0; n3 < 8; ++n3){
    int n = t + (n3 << 8);
    r[n3] = make_float2(bf2f(g[row0 + n]), bf2f(g[row1 + n]));
    r[n3 + 8] = make_float2(0.f, 0.f);
  }
  fft16<1>(r);
  #pragma unroll
  for (int k3 = 0; k3 < 16; ++k3)
    S[P16(k3*256 + hi*16 + n1)] = cmulf(r[BR4[k3]], t1c[k3], t1s[k3]);
  __syncthreads();
  #pragma unroll
  for (int n2 = 0; n2 < 16; ++n2)
    r[n2] = S[P16(hi*256 + n2*16 + n1)];
  __syncthreads();
  fft16<1>(r);
  #pragma unroll
  for (int k2 = 0; k2 < 16; ++k2)
    S[P16(k2*256 + hi*16 + n1)] = cmulf(r[BR4[k2]], t2c[k2], t2s[k2]);
  __syncthreads();
  #pragma unroll
  for (int m = 0; m < 16; ++m)
    r[m] = S[P16(hi*256 + n1*16 + m)];
  __syncthreads();
  fft16<1>(r);
  #pragma unroll
  for (int k1 = 0; k1 < 16; ++k1)
    S[P16(t + (k1 << 8))] = r[BR4[k1]];
  __syncthreads();
  float2 y[16];
  #pragma unroll
  for (int k1 = 0; k1 < 16; ++k1){
    int k = t + (k1 << 8);
    int mk1 = (t == 0) ? ((16 - k1) & 15) : (15 - k1);
    float2 Zk = r[BR4[k1]];
    float2 Zm = S[P16(mt + (mk1 << 8))];
    float2 K0 = kf0[k], K1 = kf1[k];
    float gar = 0.5f*(Zk.x + Zm.x), gai = 0.5f*(Zk.y - Zm.y);
    float gbr = 0.5f*(Zk.y + Zm.y), gbi = 0.5f*(Zm.x - Zk.x);
    float yar = gar*K0.x - gai*K0.y, yai = gar*K0.y + gai*K0.x;
    float ybr = gbr*K1.x - gbi*K1.y, ybi = gbr*K1.y + gbi*K1.x;
    y[k1] = make_float2(yar - ybi, yai + ybr);
  }
  fft16<-1>(y);
  __syncthreads();
  #pragma unroll
  for (int n3 = 0; n3 < 16; ++n3)
    S[P16(n3*256 + hi*16 + n1)] = cmulf(y[BR4[n3]], t1c[n3], -t1s[n3]);
  __syncthreads();
  #pragma unroll
  for (int m2 = 0; m2 < 16; ++m2)
    r[m2] = S[P16(hi*256 + m2*16 + n1)];
  __syncthreads();
  fft16<-1>(r);
  #pragma unroll
  for (int nn2 = 0; nn2 < 16; ++nn2)
    S[P16(nn2*256 + hi*16 + n1)] = cmulf(r[BR4[nn2]], t2c[nn2], -t2s[nn2]);
  __syncthreads();
  #pragma unroll
  for (int m = 0; m < 16; ++m)
    r[m] = S[P16(hi*256 + n1*16 + m)];
  fft16<-1>(r);
  #pragma unroll
  for (int q = 0; q < 8; ++q){
    int n = t + (q << 8);
    float2 val = r[BR4[q]];
    float g0 = bf2f(g[row0 + n]), g1 = bf2f(g[row1 + n]);
    float x00 = bf2f(x0[row0 + n]), x01 = bf2f(x0[row1 + n]);
    z[row0 + n] = f2bf((val.x + g0*fb0) * x00);
    z[row1 + n] = f2bf((val.y + g1*fb1) * x01);
  }
}

// ---- transpose z v2: (b,d,l) -> (b,l,d), 64x64 tiles, 16B coalesced IO ----
__global__ __launch_bounds__(256) void k_transpose_z(const u16* __restrict__ zin, u16* __restrict__ zout){
  __shared__ u16 S2[64 * 136];
  const int l0 = blockIdx.x * 64, d0 = blockIdx.y * 64, b = blockIdx.z;
  const int tid = threadIdx.x;
  const int rr = tid >> 3;          // 0..31
  const int ch = tid & 7;           // 16B chunk index
  // load: 16B per lane along l, rows = d
  #pragma unroll
  for (int p = 0; p < 2; ++p){
    int d = rr + p * 32;
    f32x4 v = *(const f32x4*)(zin + ((size_t)(b * DM + d0 + d)) * L_SEQ + l0 + ch * 8);
    *(f32x4*)&S2[d * 136 + ch * 8] = v;
  }
  __syncthreads();
  // store: gather column of 8 d's per lane, write 16B along d
  #pragma unroll
  for (int p = 0; p < 2; ++p){
    int l = rr + p * 32;
    int dc = ch * 8;
    short4x lo, hi2;
    #pragma unroll
    for (int j = 0; j < 4; ++j) lo[j]  = (short)S2[(dc + j) * 136 + l];
    #pragma unroll
    for (int j = 0; j < 4; ++j) hi2[j] = (short)S2[(dc + 4 + j) * 136 + l];
    u16* dst = zout + ((size_t)(b * L_SEQ + l0 + l)) * DM + d0 + dc;
    *(short4x*)dst = lo;
    *(short4x*)(dst + 4) = hi2;
  }
}

extern "C" void kernel_launch(void* const* d_in, const int* in_sizes, int n_in,
                              void* d_out, int out_size, void* d_ws, size_t ws_size,
                              hipStream_t stream){
  (void)in_sizes; (void)n_in; (void)out_size; (void)ws_size;
  const float* u       = (const float*)d_in[0];
  const float* in_w    = (const float*)d_in[1];
  const float* in_b    = (const float*)d_in[2];
  const float* short_w = (const float*)d_in[3];
  const float* short_b = (const float*)d_in[4];
  const float* w0 = (const float*)d_in[5];
  const float* b0 = (const float*)d_in[6];
  const float* f0 = (const float*)d_in[7];
  const float* w1 = (const float*)d_in[8];
  const float* b1 = (const float*)d_in[9];
  const float* f1 = (const float*)d_in[10];
  const float* w2 = (const float*)d_in[11];
  const float* b2 = (const float*)d_in[12];
  const float* f2 = (const float*)d_in[13];
  const float* w3 = (const float*)d_in[14];
  const float* fbias = (const float*)d_in[15];
  const float* out_w = (const float*)d_in[16];
  const float* out_b = (const float*)d_in[17];
  float* out = (float*)d_out;

  char* ws = (char*)d_ws;
  size_t off = 0;
  auto alloc = [&](size_t bytes)->void*{
    void* p = ws + off; off += (bytes + 255) & ~(size_t)255; return p;
  };
  const int M = BATCH * L_SEQ; // 8192
  u16*   u_bf  = (u16*)  alloc((size_t)M * DM * 2);       // later reused as z
  u16*   inwT  = (u16*)  alloc((size_t)TW * DM * 2);
  u16*   outwT = (u16*)  alloc((size_t)DM * DM * 2);
  float* H2T   = (float*)alloc((size_t)L_SEQ * 64 * 4);
  float2* Kf   = (float2*)alloc((size_t)DM * NFFT * 8);
  u16*   up    = (u16*)  alloc((size_t)M * TW * 2);       // later reused as zT
  u16*   gbuf  = (u16*)  alloc((size_t)BATCH * DM * L_SEQ * 2);
  u16*   x0buf = (u16*)  alloc((size_t)BATCH * DM * L_SEQ * 2);
  u16*   z  = u_bf;   // alias: u_bf dead after gemm1
  u16*   zT = up;     // alias: up dead after shortconv

  k_convert_u<<<2048, 256, 0, stream>>>((const float4*)u, u_bf, (M * DM) / 4);
  k_transpose_w<<<dim3(TW/32, DM/32), dim3(32, 8), 0, stream>>>(in_w, inwT, DM, TW);
  k_transpose_w<<<dim3(DM/32, DM/32), dim3(32, 8), 0, stream>>>(out_w, outwT, DM, DM);
  k_filter_h2<<<L_SEQ, 64, 0, stream>>>(w0, b0, f0, w1, b1, f1, w2, b2, f2, H2T);
  k_filter_fft16<<<DM/2, 256, 0, stream>>>(H2T, w3, Kf);
  k_gemm8<128, 384, true><<<dim3((M/128)*(TW/384)), 512, 0, stream>>>(u_bf, inwT, in_b, up, M, TW, DM);
  k_shortconv<<<dim3(L_SEQ/128, DM/64, BATCH), 256, 0, stream>>>(up, short_w, short_b, gbuf, x0buf);
  k_fftconv<<<dim3(DM/2, BATCH), 256, 0, stream>>>(gbuf, x0buf, Kf, fbias, z);
  k_transpose_z<<<dim3(L_SEQ/64, DM/64, BATCH), 256, 0, stream>>>(z, zT);
  k_gemm8<256, 128, false><<<dim3((M/256)*(DM/128)), 512, 0, stream>>>(zT, outwT, out_b, out, M, DM, DM);
}